// Round 3
// baseline (627.347 us; speedup 1.0000x reference)
//
#include <hip/hip_runtime.h>
#include <hip/hip_bf16.h>
#include <cstdint>
#include <cstddef>

// Problem constants
#define B_TOK 8192
#define HID   4096
#define NH    32
#define NKV   8
#define DH    128
#define RB    128
#define KDIM  4096
#define NOUT  5120   // q (32*128) + k (8*128) columns; v columns are never used
#define QKVW  6144

typedef __bf16 bf16x8 __attribute__((ext_vector_type(8)));
typedef __bf16 bf16x4 __attribute__((ext_vector_type(4)));
typedef float  f32x4  __attribute__((ext_vector_type(4)));

// ---- async global->LDS, 16B per lane. LDS dest = wave-uniform base + lane*16 ----
__device__ __forceinline__ void async_ld16(const void* g, void* l) {
  __builtin_amdgcn_global_load_lds(
      (__attribute__((address_space(1))) void*)(g),
      (__attribute__((address_space(3))) void*)(l), 16, 0, 0);
}

// (tanh(x)+1)/2 == sigmoid(2x) = 1/(1+exp2(-2*log2e*x))
__device__ __forceinline__ float code_of(float x) {
  const float e = exp2f(x * -2.885390081777927f);
  return __builtin_amdgcn_rcpf(1.0f + e);
}

// ---------------- fused prep kernel (unchanged) ----------------

#define NB_HID  16384
#define NB_WT   5120   // 80 n-tiles x 64 k-tiles
#define NB_HASH 64

__global__ void prep_kernel(const float* __restrict__ hidden, __bf16* __restrict__ Abf,
                            const float* __restrict__ W, __bf16* __restrict__ Wt,
                            const float* __restrict__ hw, __bf16* __restrict__ hwT) {
  __shared__ float t[64][65];
  const int bx  = blockIdx.x;
  const int tid = threadIdx.x;

  if (bx < NB_HID) {
    const int i = bx * 256 + tid;
    const float4 v0 = ((const float4*)hidden)[2 * i];
    const float4 v1 = ((const float4*)hidden)[2 * i + 1];
    bf16x8 o;
    o[0] = (__bf16)v0.x; o[1] = (__bf16)v0.y; o[2] = (__bf16)v0.z; o[3] = (__bf16)v0.w;
    o[4] = (__bf16)v1.x; o[5] = (__bf16)v1.y; o[6] = (__bf16)v1.z; o[7] = (__bf16)v1.w;
    ((bf16x8*)Abf)[i] = o;
  } else if (bx < NB_HID + NB_WT) {
    const int bt = bx - NB_HID;
    const int n0 = (bt % 80) * 64;   // over NOUT
    const int k0 = (bt / 80) * 64;   // over KDIM
    const int c4 = tid & 15;
    const int rr = tid >> 4;         // 0..15
#pragma unroll
    for (int j = 0; j < 4; ++j) {
      const int r = rr + j * 16;
      const float4 v = *(const float4*)&W[(size_t)(k0 + r) * QKVW + n0 + c4 * 4];
      t[r][c4 * 4 + 0] = v.x; t[r][c4 * 4 + 1] = v.y;
      t[r][c4 * 4 + 2] = v.z; t[r][c4 * 4 + 3] = v.w;
    }
    __syncthreads();
    const int c8 = tid & 7;
    const int nn = tid >> 3;         // 0..31
#pragma unroll
    for (int jj = 0; jj < 2; ++jj) {
      const int n = nn + jj * 32;
      bf16x8 o;
#pragma unroll
      for (int i = 0; i < 8; ++i) o[i] = (__bf16)t[c8 * 8 + i][n];
      *(bf16x8*)&Wt[(size_t)(n0 + n) * KDIM + k0 + c8 * 8] = o;
    }
  } else {
    const int idx = (bx - NB_HID - NB_WT) * 256 + tid;  // 16384 elems
    const int r = idx >> 7;    // rbit
    const int d = idx & 127;   // dim
    hwT[r * RB + d] = (__bf16)hw[(size_t)d * RB + r];   // write coalesced
  }
}

// ---------------- main GEMM: C[8192][5120] = A[8192][4096] @ Bt[5120][4096]^T + bias ----
// Round-3 change: FRAGMENT REGISTER DOUBLE-BUFFER (one K-tile deep).
//  Post-mortem r1/r2: iteration = 2505 cyc = LDS-read drain (96 ds_read_b128 ~1150cy/CU)
//  SERIALIZED ahead of MFMA block (1241cy/SIMD) -- both waves in-phase, first MFMA
//  gated on this tile's reads. Reordering within the phase (r2) changed nothing.
//  Fix: read tile t+1's fragments into a second named reg set DURING tile t's MFMAs.
//  MFMA(t) then gates on reads issued a full iteration ago (free); LDS pipe overlaps
//  matrix pipe. New floor = max(LDS ~1550, MFMA 1241) per iteration.
//  Schedule (per iter t): vmcnt(0) [retires t+1's 6 loads, issued last iter] ->
//  s_barrier -> sched_barrier(0) -> STAGE(t+2 -> s2) [s2 = slot of t-1, provably dead:
//  all waves' t-1 frag reads completed pre-barrier via lgkm gate before MFMA(t-1)] ->
//  12 ds_read frags(t+1) from s1 into NEXT regs -> 32 MFMA on CUR regs -> rotate.
//  Ping-pong X/Y via unroll-2 with named arrays (rule 20: no runtime indexing).
//  Chunk-XOR LDS swizzle + XCD swizzle kept from r1 (conflicts = 0, FETCH halved).

#define BK    32
#define KT    (KDIM / BK)       // 128
#define SLOT  24576             // A: 8192 B, B: 16384 B

__global__ __launch_bounds__(256, 2) void gemm_qk(const __bf16* __restrict__ A,
                                                  const __bf16* __restrict__ Bt,
                                                  const float* __restrict__ bias,
                                                  __bf16* __restrict__ C) {
  __shared__ __align__(1024) char smem[3 * SLOT];

  const int tid  = threadIdx.x;
  const int lane = tid & 63;
  const int wave = tid >> 6;
  const int wm   = wave >> 1;      // 0..1  (m half)
  const int wn   = wave & 1;       // 0..1  (n half)

  // XCD swizzle: bijective on 1280 = 8 xcd x (20 n x 8 m)
  const int lin = blockIdx.x;
  const int xcd = lin & 7;
  const int seq = lin >> 3;                    // 0..159
  const int m0  = (xcd * 8 + (seq & 7)) * 128;
  const int n0  = (seq >> 3) * 256;

  // staging: lane writes physical chunk (tid&3) of row (tid>>2);
  // pre-swizzled source fetches logical chunk (tid&3) ^ ((tid>>3)&3)
  const int srow = tid >> 2;                                  // 0..63
  const int sxk  = ((tid & 3) ^ ((tid >> 3) & 3)) * 8;        // elems
  const __bf16* ga = A  + (size_t)(m0 + srow) * KDIM + sxk;
  const __bf16* gb = Bt + (size_t)(n0 + srow) * KDIM + sxk;
  const int ldsA = wave * 1024;   // wave-uniform chunk within each 4KB round

#define STAGE(koff, sl) do {                                        \
    const __bf16* ga_ = ga + (koff);                                \
    const __bf16* gb_ = gb + (koff);                                \
    async_ld16(ga_,              (sl) + ldsA);                      \
    async_ld16(ga_ +  64 * KDIM, (sl) + 4096  + ldsA);              \
    async_ld16(gb_,              (sl) + 8192  + ldsA);              \
    async_ld16(gb_ +  64 * KDIM, (sl) + 12288 + ldsA);              \
    async_ld16(gb_ + 128 * KDIM, (sl) + 16384 + ldsA);              \
    async_ld16(gb_ + 192 * KDIM, (sl) + 20480 + ldsA);              \
  } while (0)

  // fragment reads: logical (row = base16 + fr, chunk hi) at physical chunk
  // hi ^ ((fr>>1)&3)  -- lane-constant XOR, zero extra VALU in the loop
  const int fr = lane & 15;
  const int xc = (lane >> 4) ^ ((fr >> 1) & 3);
  const int aoff = (wm * 64 + fr) * 64 + xc * 16;    // bytes into slot A
  const int boff = (wn * 128 + fr) * 64 + xc * 16;   // bytes into slot B region

  f32x4 acc[4][8] = {};
  bf16x8 afX[4], bfX[8], afY[4], bfY[8];

  char* s0 = smem;              // slot of tile t   (frags already in CUR regs)
  char* s1 = smem + SLOT;       // slot of tile t+1 (landed; read frags this iter)
  char* s2 = smem + 2 * SLOT;   // slot of tile t-1 (dead) -> stage target for t+2

  // body: compute tile tt from (CA,CB); read frags(tt+1) from s1 into (NA,NB)
#define BODY(tt, CA, CB, NA, NB, DO_STAGE) do {                                   \
    asm volatile("s_waitcnt vmcnt(0)" ::: "memory");                              \
    __builtin_amdgcn_s_barrier();                                                 \
    __builtin_amdgcn_sched_barrier(0);                                            \
    if (DO_STAGE) STAGE(((tt) + 2) * BK, s2);                                     \
    _Pragma("unroll")                                                             \
    for (int mi = 0; mi < 4; ++mi)                                                \
      NA[mi] = *(const bf16x8*)(s1 + aoff + mi * 1024);                           \
    _Pragma("unroll")                                                             \
    for (int ni = 0; ni < 8; ++ni)                                                \
      NB[ni] = *(const bf16x8*)(s1 + 8192 + boff + ni * 1024);                    \
    __builtin_amdgcn_s_setprio(1);                                                \
    _Pragma("unroll")                                                             \
    for (int mi = 0; mi < 4; ++mi)                                                \
      _Pragma("unroll")                                                           \
      for (int ni = 0; ni < 8; ++ni)                                              \
        acc[mi][ni] = __builtin_amdgcn_mfma_f32_16x16x32_bf16(CA[mi], CB[ni],     \
                                                              acc[mi][ni], 0, 0, 0); \
    __builtin_amdgcn_s_setprio(0);                                                \
    { char* tmp_ = s0; s0 = s1; s1 = s2; s2 = tmp_; }                             \
  } while (0)

  // prologue: stage t0,t1; wait t0 landed; read frags(t0) into X
  STAGE(0, s0);
  STAGE(BK, s1);
  asm volatile("s_waitcnt vmcnt(6)" ::: "memory");
  __builtin_amdgcn_s_barrier();
  __builtin_amdgcn_sched_barrier(0);
#pragma unroll
  for (int mi = 0; mi < 4; ++mi)
    afX[mi] = *(const bf16x8*)(s0 + aoff + mi * 1024);
#pragma unroll
  for (int ni = 0; ni < 8; ++ni)
    bfX[ni] = *(const bf16x8*)(s0 + 8192 + boff + ni * 1024);

  // main loop: bodies t = 0..125 (all stage t+2 <= 127)
  for (int t = 0; t < KT - 2; t += 2) {
    BODY(t,     afX, bfX, afY, bfY, true);
    BODY(t + 1, afY, bfY, afX, bfX, true);
  }
  // t = 126: no stage; reads frags(127)
  BODY(KT - 2, afX, bfX, afY, bfY, false);
  // t = 127: pure compute on Y (frags read in previous body; lgkm gate by compiler)
  __builtin_amdgcn_s_setprio(1);
#pragma unroll
  for (int mi = 0; mi < 4; ++mi)
#pragma unroll
    for (int ni = 0; ni < 8; ++ni)
      acc[mi][ni] = __builtin_amdgcn_mfma_f32_16x16x32_bf16(afY[mi], bfY[ni],
                                                            acc[mi][ni], 0, 0, 0);
  __builtin_amdgcn_s_setprio(0);

#undef STAGE
#undef BODY

  // epilogue: D layout col=lane&15, row=(lane>>4)*4+reg
  const int cl = lane & 15;
  const int rq = (lane >> 4) * 4;
#pragma unroll
  for (int ni = 0; ni < 8; ++ni) {
    const int gn = n0 + wn * 128 + ni * 16 + cl;
    const float bb = bias[gn];
#pragma unroll
    for (int mi = 0; mi < 4; ++mi) {
      const int gm = m0 + wm * 64 + mi * 16 + rq;
#pragma unroll
      for (int r = 0; r < 4; ++r)
        C[(size_t)(gm + r) * NOUT + gn] = (__bf16)(acc[mi][ni][r] + bb);
    }
  }
}

// ---------------- phase 2: per-token dots/norms/hash codes (unchanged) ----------------

__global__ void phase2_kernel(const __bf16* __restrict__ QK,
                              const __bf16* __restrict__ hwT,
                              float* __restrict__ out) {
  __shared__ __bf16 As[48][136];    // +8 bf16 pad -> conflict-free ds_read_b128
  __shared__ float code[40][132];   // (tanh+1)/2 codes
  __shared__ float rednorm[40];
  __shared__ float reddot[32];

  const int tid  = threadIdx.x;
  const int lane = tid & 63;
  const int wave = tid >> 6;
  const int b = blockIdx.x;

  const __bf16* src = QK + (size_t)b * NOUT;
  for (int i = tid; i < 640; i += 256) {
    const int row = i >> 4;
    const int col = (i & 15) * 8;
    *(uint4*)(&As[row][col]) = *(const uint4*)(src + i * 8);
  }

  const int fr = lane & 15;
  const int fk = (lane >> 4) * 8;
  bf16x8 bf[2][4];
#pragma unroll
  for (int nn = 0; nn < 2; ++nn) {
    const int ni = wave + nn * 4;
#pragma unroll
    for (int ks = 0; ks < 4; ++ks)
      bf[nn][ks] = *(const bf16x8*)(hwT + (size_t)(ni * 16 + fr) * RB + ks * 32 + fk);
  }
  __syncthreads();

#pragma unroll
  for (int mi = 0; mi < 3; ++mi) {
    bf16x8 af[4];
#pragma unroll
    for (int ks = 0; ks < 4; ++ks)
      af[ks] = *(const bf16x8*)(&As[mi * 16 + fr][ks * 32 + fk]);
#pragma unroll
    for (int nn = 0; nn < 2; ++nn) {
      const int ni = wave + nn * 4;
      f32x4 acc = {0.f, 0.f, 0.f, 0.f};
#pragma unroll
      for (int ks = 0; ks < 4; ++ks)
        acc = __builtin_amdgcn_mfma_f32_16x16x32_bf16(af[ks], bf[nn][ks], acc, 0, 0, 0);
      const int row0 = mi * 16 + (lane >> 4) * 4;
      const int col  = ni * 16 + (lane & 15);
#pragma unroll
      for (int r = 0; r < 4; ++r) {
        const int row = row0 + r;
        if (row < 40) code[row][col] = code_of(acc[r]);
      }
    }
  }

  {
    const int q = lane >> 4;
    const int c = lane & 15;
    const int ti = (wave == 1 || wave == 3) ? 1 : 0;
    const int tj = (wave >= 2) ? 2 : ti;
    bf16x8 fa[4], fb[4];
#pragma unroll
    for (int ks = 0; ks < 4; ++ks) {
      fa[ks] = *(const bf16x8*)(&As[ti * 16 + fr][ks * 32 + fk]);
      fb[ks] = *(const bf16x8*)(&As[tj * 16 + fr][ks * 32 + fk]);
    }
    f32x4 g = {0.f, 0.f, 0.f, 0.f};
#pragma unroll
    for (int ks = 0; ks < 4; ++ks)
      g = __builtin_amdgcn_mfma_f32_16x16x32_bf16(fa[ks], fb[ks], g, 0, 0, 0);
    if (ti == tj) {
      if ((c >> 2) == q) rednorm[ti * 16 + c] = g[c & 3];
    } else {
      if (c == ti * 4 + q) {
#pragma unroll
        for (int r = 0; r < 4; ++r) reddot[ti * 16 + q * 4 + r] = g[r];
      }
    }
    if (wave == 0) {
      bf16x8 fc[4];
#pragma unroll
      for (int ks = 0; ks < 4; ++ks)
        fc[ks] = *(const bf16x8*)(&As[32 + fr][ks * 32 + fk]);
      f32x4 g2 = {0.f, 0.f, 0.f, 0.f};
#pragma unroll
      for (int ks = 0; ks < 4; ++ks)
        g2 = __builtin_amdgcn_mfma_f32_16x16x32_bf16(fc[ks], fc[ks], g2, 0, 0, 0);
      if ((c >> 2) == q && c < 8) rednorm[32 + c] = g2[c & 3];
    }
  }
  __syncthreads();

  const int h   = tid >> 3;
  const int sub = tid & 7;
  const int kr  = 32 + (h >> 2);
  float s = 0.f;
#pragma unroll
  for (int j = 0; j < 16; ++j) {
    const int c = sub + 8 * j;
    s += fabsf(code[h][c] - code[kr][c]);
  }
  s += __shfl_down(s, 4, 8);
  s += __shfl_down(s, 2, 8);
  s += __shfl_down(s, 1, 8);
  if (sub == 0) {
    const float invsq = 0.08838834764831843f;  // 1/sqrt(128)
    out[(size_t)b * NH + h] = reddot[h] * invsq;
    const float hamw = (1.0f - s * (1.0f / 64.0f)) *
                       sqrtf(rednorm[h]) * sqrtf(rednorm[kr]) * invsq;
    out[(size_t)(B_TOK * NH) + (size_t)b * NH + h] = hamw;
  }
}

// ---------------- launch ----------------

extern "C" void kernel_launch(void* const* d_in, const int* in_sizes, int n_in,
                              void* d_out, int out_size, void* d_ws, size_t ws_size,
                              hipStream_t stream) {
  const float* hidden = (const float*)d_in[0];   // [8192][4096]
  const float* proj_w = (const float*)d_in[1];   // [4096][6144]
  const float* proj_b = (const float*)d_in[2];   // [6144]
  const float* hash_w = (const float*)d_in[3];   // [128][128]
  float* out = (float*)d_out;                    // [2*262144]

  char* w = (char*)d_ws;
  __bf16* Abf = (__bf16*)(w);                                     // 67,108,864 B
  __bf16* Wt  = (__bf16*)(w + 67108864);                          // 41,943,040 B
  __bf16* QK  = (__bf16*)(w + 67108864 + 41943040);               // 83,886,080 B
  __bf16* hwT = (__bf16*)(w + 67108864 + 41943040 + 83886080);    // 32,768 B

  prep_kernel<<<NB_HID + NB_WT + NB_HASH, 256, 0, stream>>>(hidden, Abf, proj_w, Wt,
                                                            hash_w, hwT);
  gemm_qk<<<1280, 256, 0, stream>>>(Abf, Wt, proj_b, QK);
  phase2_kernel<<<B_TOK, 256, 0, stream>>>(QK, hwT, out);
}

// Round 4
// 573.469 us; speedup vs baseline: 1.0939x; 1.0939x over previous
//
#include <hip/hip_runtime.h>
#include <hip/hip_bf16.h>
#include <cstdint>
#include <cstddef>

// Problem constants
#define B_TOK 8192
#define HID   4096
#define NH    32
#define NKV   8
#define DH    128
#define RB    128
#define KDIM  4096
#define NOUT  5120   // q (32*128) + k (8*128) columns; v columns are never used
#define QKVW  6144

typedef __bf16 bf16x8 __attribute__((ext_vector_type(8)));
typedef float  f32x4  __attribute__((ext_vector_type(4)));

// ---- async global->LDS, 16B per lane. LDS dest = wave-uniform base + lane*16 ----
__device__ __forceinline__ void async_ld16(const void* g, void* l) {
  __builtin_amdgcn_global_load_lds(
      (__attribute__((address_space(1))) void*)(g),
      (__attribute__((address_space(3))) void*)(l), 16, 0, 0);
}

// (tanh(x)+1)/2 == sigmoid(2x) = 1/(1+exp2(-2*log2e*x))
__device__ __forceinline__ float code_of(float x) {
  const float e = exp2f(x * -2.885390081777927f);
  return __builtin_amdgcn_rcpf(1.0f + e);
}

// ---------------- fused prep kernel (unchanged) ----------------

#define NB_HID  16384
#define NB_WT   5120   // 80 n-tiles x 64 k-tiles
#define NB_HASH 64

__global__ void prep_kernel(const float* __restrict__ hidden, __bf16* __restrict__ Abf,
                            const float* __restrict__ W, __bf16* __restrict__ Wt,
                            const float* __restrict__ hw, __bf16* __restrict__ hwT) {
  __shared__ float t[64][65];
  const int bx  = blockIdx.x;
  const int tid = threadIdx.x;

  if (bx < NB_HID) {
    const int i = bx * 256 + tid;
    const float4 v0 = ((const float4*)hidden)[2 * i];
    const float4 v1 = ((const float4*)hidden)[2 * i + 1];
    bf16x8 o;
    o[0] = (__bf16)v0.x; o[1] = (__bf16)v0.y; o[2] = (__bf16)v0.z; o[3] = (__bf16)v0.w;
    o[4] = (__bf16)v1.x; o[5] = (__bf16)v1.y; o[6] = (__bf16)v1.z; o[7] = (__bf16)v1.w;
    ((bf16x8*)Abf)[i] = o;
  } else if (bx < NB_HID + NB_WT) {
    const int bt = bx - NB_HID;
    const int n0 = (bt % 80) * 64;   // over NOUT
    const int k0 = (bt / 80) * 64;   // over KDIM
    const int c4 = tid & 15;
    const int rr = tid >> 4;         // 0..15
#pragma unroll
    for (int j = 0; j < 4; ++j) {
      const int r = rr + j * 16;
      const float4 v = *(const float4*)&W[(size_t)(k0 + r) * QKVW + n0 + c4 * 4];
      t[r][c4 * 4 + 0] = v.x; t[r][c4 * 4 + 1] = v.y;
      t[r][c4 * 4 + 2] = v.z; t[r][c4 * 4 + 3] = v.w;
    }
    __syncthreads();
    const int c8 = tid & 7;
    const int nn = tid >> 3;         // 0..31
#pragma unroll
    for (int jj = 0; jj < 2; ++jj) {
      const int n = nn + jj * 32;
      bf16x8 o;
#pragma unroll
      for (int i = 0; i < 8; ++i) o[i] = (__bf16)t[c8 * 8 + i][n];
      *(bf16x8*)&Wt[(size_t)(n0 + n) * KDIM + k0 + c8 * 8] = o;
    }
  } else {
    const int idx = (bx - NB_HID - NB_WT) * 256 + tid;  // 16384 elems
    const int r = idx >> 7;    // rbit
    const int d = idx & 127;   // dim
    hwT[r * RB + d] = (__bf16)hw[(size_t)d * RB + r];   // write coalesced
  }
}

// ---------------- main GEMM: C[8192][5120] = A[8192][4096] @ Bt[5120][4096]^T + bias ----
// Round-4: m201-style PHASED schedule + bigger tile (BM=256, BN=320, BK=64).
//  r1-r3 post-mortem: per-wave 64x128 geometry is LDS-roofline-bound (F/B=42.7;
//  LDS pipe 1730cy vs MFMA 1241cy per K-tile per CU) and the flat 2-barrier
//  structure serializes the two pipes -> 48% MfmaUtil no matter the ordering.
//  New geometry: 8 waves (2Mx4N), per-wave 128x80 -> F/B=49.2; per CU per K-tile:
//  LDS ~3200cy vs MFMA ~3100cy/SIMD -> ~92% balance ceiling.
//  Grid 32x16=512 = exactly 2 rounds of 256 CUs, zero tail. LDS ring-2 = 144KB.
//  Per K-tile: 4 phases, each {4 A-frag ds_reads; 3 stage rounds; barrier;
//  lgkmcnt(0); sched_barrier; 20 MFMA; barrier}. B-frags (10 reads) loaded at P0,
//  held in regs. Overlap mechanism = wave skew within phase (small read batches).
//  Single vmcnt(0) after P3's MFMA: >=1550cy after last stage issue -> ~free;
//  P3 end-barrier publishes slot t+1 for next tile's pre-barrier reads.
//  Chunk-XOR swizzle (chunk ^= row&7, both-sides) + XCD n-strip swizzle kept.

#define BKT   64
#define NKT   (KDIM / BKT)      // 64 K-tiles
#define ASZ   32768             // 256 x 64 x 2B
#define BSZ   40960             // 320 x 64 x 2B
#define SLOT2 (ASZ + BSZ)       // 73728

__global__ __launch_bounds__(512, 2) void gemm_qk(const __bf16* __restrict__ A,
                                                  const __bf16* __restrict__ Bt,
                                                  const float* __restrict__ bias,
                                                  __bf16* __restrict__ C) {
  __shared__ __align__(1024) char smem[2 * SLOT2];   // 144 KB

  const int tid  = threadIdx.x;
  const int lane = tid & 63;
  const int wave = tid >> 6;       // 0..7
  const int wm   = wave >> 2;      // 0..1  (m half: 128 rows)
  const int wn   = wave & 3;       // 0..3  (n quarter: 80 cols)

  // XCD swizzle: 512 = 8 xcd x (2 n x 32 m); each XCD owns a 640-row B strip (~5MB)
  const int lin = blockIdx.x;
  const int xcd = lin & 7;
  const int seq = lin >> 3;                    // 0..63
  const int n0  = (xcd * 2 + (seq & 1)) * 320;
  const int m0  = (seq >> 1) * 256;

  // staging: 512 lanes x 16B = 8KB/round = 64 rows x 64k. Lane: row=tid>>3,
  // phys chunk=tid&7; pre-swizzled source logical chunk = (tid&7)^((tid>>3)&7).
  const int sxk = ((tid & 7) ^ ((tid >> 3) & 7)) * 8;          // elems
  const __bf16* ga0 = A  + (size_t)(m0 + (tid >> 3)) * KDIM + sxk;
  const __bf16* gb0 = Bt + (size_t)(n0 + (tid >> 3)) * KDIM + sxk;
  const int ldsw = wave * 1024;    // wave-uniform offset within each 8KB round

#define STG_A(r, dst, kk) async_ld16(ga0 + (size_t)(r) * 64 * KDIM + (kk), \
                                     (dst) + (r) * 8192 + ldsw)
#define STG_B(r, dst, kk) async_ld16(gb0 + (size_t)(r) * 64 * KDIM + (kk), \
                                     (dst) + ASZ + (r) * 8192 + ldsw)

  // fragment reads: row = base + fr; 16B chunk c = ks*4 + hi read at phys
  // c ^ (fr&7) (bases are 0 mod 8) -> 16 lanes spread over 8 chunk slots = 2-way.
  const int fr = lane & 15;
  const int hi = lane >> 4;
  const int xk0 = ((0 * 4 + hi) ^ (fr & 7)) * 16;
  const int xk1 = ((1 * 4 + hi) ^ (fr & 7)) * 16;
  const int aoffb = (wm * 128 + fr) * 128;     // bytes into A region
  const int boffb = (wn * 80 + fr) * 128;      // bytes into B region

#define LD_A(mi, xk) (*(const bf16x8*)(sc + aoffb + (mi) * 2048 + (xk)))
#define LD_B(ni, xk) (*(const bf16x8*)(sc + ASZ + boffb + (ni) * 2048 + (xk)))
#define SB()    __builtin_amdgcn_sched_barrier(0)
#define BAR()   __builtin_amdgcn_s_barrier()
#define LGKM0() asm volatile("s_waitcnt lgkmcnt(0)" ::: "memory")

  f32x4 acc[8][5] = {};
  bf16x8 bf[5][2];

  // phase p computes mi = 2p, 2p+1  (20 MFMA: ks x l x ni)
#define PHASE_MFMA(P) do {                                                        \
    __builtin_amdgcn_s_setprio(1);                                                \
    _Pragma("unroll")                                                             \
    for (int ks = 0; ks < 2; ++ks)                                                \
      _Pragma("unroll")                                                           \
      for (int l = 0; l < 2; ++l)                                                 \
        _Pragma("unroll")                                                         \
        for (int ni = 0; ni < 5; ++ni)                                            \
          acc[2*(P)+l][ni] = __builtin_amdgcn_mfma_f32_16x16x32_bf16(             \
              af[l][ks], bf[ni][ks], acc[2*(P)+l][ni], 0, 0, 0);                  \
    __builtin_amdgcn_s_setprio(0);                                                \
  } while (0)

#define PHASE_READ_A(P) do {                                                      \
    af[0][0] = LD_A(2*(P),     xk0); af[0][1] = LD_A(2*(P),     xk1);             \
    af[1][0] = LD_A(2*(P) + 1, xk0); af[1][1] = LD_A(2*(P) + 1, xk1);             \
  } while (0)

  // prologue: stage tile 0 into slot 0, drain, publish
  {
    char* d = smem;
#pragma unroll
    for (int r = 0; r < 4; ++r) STG_A(r, d, 0);
#pragma unroll
    for (int r = 0; r < 5; ++r) STG_B(r, d, 0);
  }
  asm volatile("s_waitcnt vmcnt(0)" ::: "memory");
  BAR();
  SB();

  for (int t = 0; t < NKT; ++t) {
    const bool st = (t < NKT - 1);
    char* sc = smem + (t & 1) * SLOT2;
    char* sn = smem + ((t + 1) & 1) * SLOT2;
    const int kk = (t + 1) * BKT;
    bf16x8 af[2][2];

    // ---- P0: B frags + A(mi 0,1); stage A rounds 0-2 ----
#pragma unroll
    for (int ni = 0; ni < 5; ++ni) {
      bf[ni][0] = LD_B(ni, xk0);
      bf[ni][1] = LD_B(ni, xk1);
    }
    PHASE_READ_A(0);
    SB();
    if (st) { STG_A(0, sn, kk); STG_A(1, sn, kk); STG_A(2, sn, kk); }
    SB();
    BAR(); LGKM0(); SB();
    PHASE_MFMA(0);
    SB(); BAR();

    // ---- P1: A(mi 2,3); stage A3, B0, B1 ----
    PHASE_READ_A(1);
    SB();
    if (st) { STG_A(3, sn, kk); STG_B(0, sn, kk); STG_B(1, sn, kk); }
    SB();
    BAR(); LGKM0(); SB();
    PHASE_MFMA(1);
    SB(); BAR();

    // ---- P2: A(mi 4,5); stage B2, B3, B4 ----
    PHASE_READ_A(2);
    SB();
    if (st) { STG_B(2, sn, kk); STG_B(3, sn, kk); STG_B(4, sn, kk); }
    SB();
    BAR(); LGKM0(); SB();
    PHASE_MFMA(2);
    SB(); BAR();

    // ---- P3: A(mi 6,7); drain stage (issued >=1.5 phases ago); publish slot ----
    PHASE_READ_A(3);
    SB();
    BAR(); LGKM0(); SB();
    PHASE_MFMA(3);
    if (st) asm volatile("s_waitcnt vmcnt(0)" ::: "memory");
    BAR();
    SB();
  }

#undef STG_A
#undef STG_B
#undef LD_A
#undef LD_B
#undef PHASE_MFMA
#undef PHASE_READ_A

  // epilogue: D layout col=lane&15, row=(lane>>4)*4+reg
  const int cl = lane & 15;
  const int rq = hi * 4;
#pragma unroll
  for (int ni = 0; ni < 5; ++ni) {
    const int gn = n0 + wn * 80 + ni * 16 + cl;
    const float bb = bias[gn];
#pragma unroll
    for (int mi = 0; mi < 8; ++mi) {
      const int gm = m0 + wm * 128 + mi * 16 + rq;
#pragma unroll
      for (int r = 0; r < 4; ++r)
        C[(size_t)(gm + r) * NOUT + gn] = (__bf16)(acc[mi][ni][r] + bb);
    }
  }
}

// ---------------- phase 2: per-token dots/norms/hash codes (unchanged) ----------------

__global__ void phase2_kernel(const __bf16* __restrict__ QK,
                              const __bf16* __restrict__ hwT,
                              float* __restrict__ out) {
  __shared__ __bf16 As[48][136];    // +8 bf16 pad -> conflict-free ds_read_b128
  __shared__ float code[40][132];   // (tanh+1)/2 codes
  __shared__ float rednorm[40];
  __shared__ float reddot[32];

  const int tid  = threadIdx.x;
  const int lane = tid & 63;
  const int wave = tid >> 6;
  const int b = blockIdx.x;

  const __bf16* src = QK + (size_t)b * NOUT;
  for (int i = tid; i < 640; i += 256) {
    const int row = i >> 4;
    const int col = (i & 15) * 8;
    *(uint4*)(&As[row][col]) = *(const uint4*)(src + i * 8);
  }

  const int fr = lane & 15;
  const int fk = (lane >> 4) * 8;
  bf16x8 bf[2][4];
#pragma unroll
  for (int nn = 0; nn < 2; ++nn) {
    const int ni = wave + nn * 4;
#pragma unroll
    for (int ks = 0; ks < 4; ++ks)
      bf[nn][ks] = *(const bf16x8*)(hwT + (size_t)(ni * 16 + fr) * RB + ks * 32 + fk);
  }
  __syncthreads();

#pragma unroll
  for (int mi = 0; mi < 3; ++mi) {
    bf16x8 af[4];
#pragma unroll
    for (int ks = 0; ks < 4; ++ks)
      af[ks] = *(const bf16x8*)(&As[mi * 16 + fr][ks * 32 + fk]);
#pragma unroll
    for (int nn = 0; nn < 2; ++nn) {
      const int ni = wave + nn * 4;
      f32x4 acc = {0.f, 0.f, 0.f, 0.f};
#pragma unroll
      for (int ks = 0; ks < 4; ++ks)
        acc = __builtin_amdgcn_mfma_f32_16x16x32_bf16(af[ks], bf[nn][ks], acc, 0, 0, 0);
      const int row0 = mi * 16 + (lane >> 4) * 4;
      const int col  = ni * 16 + (lane & 15);
#pragma unroll
      for (int r = 0; r < 4; ++r) {
        const int row = row0 + r;
        if (row < 40) code[row][col] = code_of(acc[r]);
      }
    }
  }

  {
    const int q = lane >> 4;
    const int c = lane & 15;
    const int ti = (wave == 1 || wave == 3) ? 1 : 0;
    const int tj = (wave >= 2) ? 2 : ti;
    bf16x8 fa[4], fb[4];
#pragma unroll
    for (int ks = 0; ks < 4; ++ks) {
      fa[ks] = *(const bf16x8*)(&As[ti * 16 + fr][ks * 32 + fk]);
      fb[ks] = *(const bf16x8*)(&As[tj * 16 + fr][ks * 32 + fk]);
    }
    f32x4 g = {0.f, 0.f, 0.f, 0.f};
#pragma unroll
    for (int ks = 0; ks < 4; ++ks)
      g = __builtin_amdgcn_mfma_f32_16x16x32_bf16(fa[ks], fb[ks], g, 0, 0, 0);
    if (ti == tj) {
      if ((c >> 2) == q) rednorm[ti * 16 + c] = g[c & 3];
    } else {
      if (c == ti * 4 + q) {
#pragma unroll
        for (int r = 0; r < 4; ++r) reddot[ti * 16 + q * 4 + r] = g[r];
      }
    }
    if (wave == 0) {
      bf16x8 fc[4];
#pragma unroll
      for (int ks = 0; ks < 4; ++ks)
        fc[ks] = *(const bf16x8*)(&As[32 + fr][ks * 32 + fk]);
      f32x4 g2 = {0.f, 0.f, 0.f, 0.f};
#pragma unroll
      for (int ks = 0; ks < 4; ++ks)
        g2 = __builtin_amdgcn_mfma_f32_16x16x32_bf16(fc[ks], fc[ks], g2, 0, 0, 0);
      if ((c >> 2) == q && c < 8) rednorm[32 + c] = g2[c & 3];
    }
  }
  __syncthreads();

  const int h   = tid >> 3;
  const int sub = tid & 7;
  const int kr  = 32 + (h >> 2);
  float s = 0.f;
#pragma unroll
  for (int j = 0; j < 16; ++j) {
    const int c = sub + 8 * j;
    s += fabsf(code[h][c] - code[kr][c]);
  }
  s += __shfl_down(s, 4, 8);
  s += __shfl_down(s, 2, 8);
  s += __shfl_down(s, 1, 8);
  if (sub == 0) {
    const float invsq = 0.08838834764831843f;  // 1/sqrt(128)
    out[(size_t)b * NH + h] = reddot[h] * invsq;
    const float hamw = (1.0f - s * (1.0f / 64.0f)) *
                       sqrtf(rednorm[h]) * sqrtf(rednorm[kr]) * invsq;
    out[(size_t)(B_TOK * NH) + (size_t)b * NH + h] = hamw;
  }
}

// ---------------- launch ----------------

extern "C" void kernel_launch(void* const* d_in, const int* in_sizes, int n_in,
                              void* d_out, int out_size, void* d_ws, size_t ws_size,
                              hipStream_t stream) {
  const float* hidden = (const float*)d_in[0];   // [8192][4096]
  const float* proj_w = (const float*)d_in[1];   // [4096][6144]
  const float* proj_b = (const float*)d_in[2];   // [6144]
  const float* hash_w = (const float*)d_in[3];   // [128][128]
  float* out = (float*)d_out;                    // [2*262144]

  char* w = (char*)d_ws;
  __bf16* Abf = (__bf16*)(w);                                     // 67,108,864 B
  __bf16* Wt  = (__bf16*)(w + 67108864);                          // 41,943,040 B
  __bf16* QK  = (__bf16*)(w + 67108864 + 41943040);               // 83,886,080 B
  __bf16* hwT = (__bf16*)(w + 67108864 + 41943040 + 83886080);    // 32,768 B

  prep_kernel<<<NB_HID + NB_WT + NB_HASH, 256, 0, stream>>>(hidden, Abf, proj_w, Wt,
                                                            hash_w, hwT);
  gemm_qk<<<512, 512, 0, stream>>>(Abf, Wt, proj_b, QK);
  phase2_kernel<<<B_TOK, 256, 0, stream>>>(QK, hwT, out);
}